// Round 4
// baseline (1097.599 us; speedup 1.0000x reference)
//
#include <hip/hip_runtime.h>

#define L_SEQ 2048
#define DMODEL 2048
#define NHEAD 16
#define HDIM 128
#define BATCH 4

typedef _Float16 f16x8 __attribute__((ext_vector_type(8)));
typedef _Float16 f16x4 __attribute__((ext_vector_type(4)));
typedef float f32x4 __attribute__((ext_vector_type(4)));

// async global->LDS, 16B per lane. LDS base must be wave-uniform; HW scatters lane*16.
__device__ __forceinline__ void gload16(const void* g, void* l) {
  __builtin_amdgcn_global_load_lds((const __attribute__((address_space(1))) void*)g,
                                   (__attribute__((address_space(3))) void*)l, 16, 0, 0);
}

__global__ void cvt_f32_f16(const float* __restrict__ in, _Float16* __restrict__ out, int n) {
  int i = (blockIdx.x * 256 + threadIdx.x) * 4;
  if (i >= n) return;
  float4 v = *(const float4*)(in + i);
  f16x4 o;
  o[0] = (_Float16)v.x; o[1] = (_Float16)v.y; o[2] = (_Float16)v.z; o[3] = (_Float16)v.w;
  *(f16x4*)(out + i) = o;
}

// C[M][N] = A[M][K] * Bt[N][K]^T  (both row-major, fp16 in, OUT out)
// 128x128 tile, BK=64, 256 threads = 4 waves in 2x2, each wave 64x64 via 4x4 mfma_16x16x32.
// LDS k-blocked layout: elem (row,k) at 16B-unit index (k/8)*128 + row, byte (k%8)*2 within.
// 1-D grid + XCD-aware group-M swizzle: blockIdx%8 = XCD class -> contiguous 8-M-tile slab,
// M fastest within slab. Concurrent blocks per XCD cover ~8x16 tiles: A-slabs disjoint per
// XCD (kills cross-XCD A duplication in L2), tile slices shared 8-16x among resident blocks.
// REQUIRES M/128 == 64 (8 M-tiles per XCD slab); guarded below anyway.
template <typename OUT>
__global__ __launch_bounds__(256, 4) void gemm_bt(const _Float16* __restrict__ A,
                                                  const _Float16* __restrict__ Bt,
                                                  OUT* __restrict__ C,
                                                  int M, int N, int K) {
  __shared__ _Float16 As[128 * 64];
  __shared__ _Float16 Bs[128 * 64];
  const int tid = threadIdx.x;
  const int wave = tid >> 6, lane = tid & 63, quad = lane >> 4, l15 = lane & 15;
  const int xcd = blockIdx.x & 7;
  const int lm = blockIdx.x >> 3;          // 0 .. tiles_n*8-1
  const int tm = xcd * 8 + (lm & 7);       // M-tile within this XCD's slab
  const int tn = lm >> 3;                  // N-tile
  if (tm * 128 >= M || tn * 128 >= N) return;  // wave-uniform safety guard
  const int m0 = tm << 7, n0 = tn << 7;
  const int wm = (wave >> 1) * 64, wn = (wave & 1) * 64;
  f32x4 acc[4][4] = {};
  for (int k0 = 0; k0 < K; k0 += 64) {
    __syncthreads();  // prev-iter LDS reads done before overwrite
    for (int j = 0; j < 4; ++j) {
      int id = wave * 4 + j;
      int kb = id >> 1, r0 = (id & 1) * 64;
      gload16(A + (size_t)(m0 + r0 + lane) * K + (k0 + kb * 8), (char*)As + (kb * 128 + r0) * 16);
      gload16(Bt + (size_t)(n0 + r0 + lane) * K + (k0 + kb * 8), (char*)Bs + (kb * 128 + r0) * 16);
    }
    __syncthreads();  // compiler drains vmcnt before barrier
    const f16x8* A8 = (const f16x8*)As;
    const f16x8* B8 = (const f16x8*)Bs;
    for (int kk = 0; kk < 2; ++kk) {
      int kb = kk * 4 + quad;
      f16x8 af[4], bf[4];
      for (int mi = 0; mi < 4; ++mi) af[mi] = A8[kb * 128 + wm + mi * 16 + l15];
      for (int ni = 0; ni < 4; ++ni) bf[ni] = B8[kb * 128 + wn + ni * 16 + l15];
      for (int mi = 0; mi < 4; ++mi)
        for (int ni = 0; ni < 4; ++ni)
          acc[mi][ni] = __builtin_amdgcn_mfma_f32_16x16x32_f16(af[mi], bf[ni], acc[mi][ni], 0, 0, 0);
    }
  }
  // C/D layout: col = lane&15, row = quad*4 + reg  (m89-verified, dtype-independent)
  for (int mi = 0; mi < 4; ++mi)
    for (int ni = 0; ni < 4; ++ni) {
      int r = m0 + wm + mi * 16 + quad * 4;
      int c = n0 + wn + ni * 16 + l15;
      for (int reg = 0; reg < 4; ++reg)
        C[(size_t)(r + reg) * N + c] = (OUT)acc[mi][ni][reg];
    }
}

// qkv[8192][6144] fp16, q/k part only -> rope -> qt,kt:[bh][l][hd]   (coalesced both sides)
__global__ void rope_scatter(const _Float16* __restrict__ qkv,
                             _Float16* __restrict__ qt,
                             _Float16* __restrict__ kt) {
  int row = blockIdx.x;                       // 0..8191 = b*2048 + l
  int pe = blockIdx.y * 256 + threadIdx.x;    // 0..2047 pair index (q,k only)
  int e = pe * 2;
  float x1 = (float)qkv[(size_t)row * 6144 + e];
  float x2 = (float)qkv[(size_t)row * 6144 + e + 1];
  int which = e >> 11;                        // 0=q, 1=k
  int h = (e >> 7) & 15;
  int hd = e & 127;
  int b = row >> 11, l = row & 2047;
  int bh = b * 16 + h;
  int i = hd >> 1;
  // freq = 10000^(-i/64) ; ln(10000)/64 = 0.14391156831212787
  float ang = (float)l * __expf((float)i * -0.14391156831212787f);
  float s, c;
  __sincosf(ang, &s, &c);
  float o1 = x1 * c - x2 * s;
  float o2 = x2 * c + x1 * s;
  _Float16* dst = (which == 0) ? qt : kt;
  size_t base = ((size_t)bh * 2048 + l) * 128 + hd;
  dst[base] = (_Float16)o1;
  dst[base + 1] = (_Float16)o2;
}

// V part of qkv -> vt[bh][hd][l], LDS-tiled 64x64 transpose, coalesced global R/W.
// LDS row pad 72 elems (144B, 16B-aligned) to break transposed-read bank conflicts.
__global__ __launch_bounds__(256) void v_transpose(const _Float16* __restrict__ qkv,
                                                   _Float16* __restrict__ vt) {
  __shared__ _Float16 Ls[64 * 72];
  const int tid = threadIdx.x;
  const int l0 = blockIdx.x * 64;       // 32 tiles
  const int hd0 = blockIdx.y * 64;      // 2 tiles
  const int bh = blockIdx.z;            // 64
  const int b = bh >> 4, h = bh & 15;
  const size_t colbase = 4096 + h * 128 + hd0;
  for (int i = 0; i < 2; ++i) {
    int chunk = tid + i * 256;
    int r = chunk >> 3, c = chunk & 7;
    f16x8 v = *(const f16x8*)(qkv + (size_t)(b * 2048 + l0 + r) * 6144 + colbase + c * 8);
    *(f16x8*)(Ls + r * 72 + c * 8) = v;
  }
  __syncthreads();
  for (int i = 0; i < 2; ++i) {
    int chunk = tid + i * 256;
    int hr = chunk >> 3, c = chunk & 7;
    f16x8 o;
    for (int j = 0; j < 8; ++j) o[j] = Ls[(c * 8 + j) * 72 + hr];
    *(f16x8*)(vt + ((size_t)bh * 128 + hd0 + hr) * 2048 + l0 + c * 8) = o;
  }
}

// Flash attention, causal. Block: 64 q rows (4 waves x 16), KV tiles of 64.
// K LDS: hd-blocked  (hd/8)*64 + kv ; V LDS (from vt[hd][l]): kv-blocked (kv/8)*128 + hd.
// P (C-layout) -> per-wave LDS (k-blocked) -> reread as A-operand fragments.
__global__ __launch_bounds__(256) void attn_fwd(const _Float16* __restrict__ qt,
                                                const _Float16* __restrict__ kt,
                                                const _Float16* __restrict__ vt,
                                                _Float16* __restrict__ y) {
  __shared__ _Float16 Kl[64 * 128];
  __shared__ _Float16 Vl[64 * 128];
  __shared__ _Float16 Pl[4 * 16 * 64];
  const int q0 = blockIdx.x * 64;
  const int bh = blockIdx.y;
  const int tid = threadIdx.x;
  const int wave = tid >> 6, lane = tid & 63, quad = lane >> 4, l15 = lane & 15;
  const _Float16* Q = qt + (size_t)bh * L_SEQ * HDIM;
  const _Float16* Kg = kt + (size_t)bh * L_SEQ * HDIM;
  const _Float16* Vg = vt + (size_t)bh * HDIM * L_SEQ;

  // Q fragments (A-operand): lane holds Q[q0+wave*16+l15][kk*32+quad*8 .. +8]
  f16x8 qf[4];
  {
    int qrow = q0 + wave * 16 + l15;
    for (int kk = 0; kk < 4; ++kk)
      qf[kk] = *(const f16x8*)(Q + (size_t)qrow * 128 + kk * 32 + quad * 8);
  }
  f32x4 o[8] = {};
  float mi[4] = {-1e30f, -1e30f, -1e30f, -1e30f};
  float li[4] = {0.f, 0.f, 0.f, 0.f};
  const float scale = 0.08838834764831845f;  // 1/sqrt(128)
  const int ntile = (q0 >> 6) + 1;

  for (int t = 0; t < ntile; ++t) {
    const int kv0 = t * 64;
    __syncthreads();
    for (int j = 0; j < 4; ++j) {
      int id = wave * 4 + j;
      // K tile: 16 wave-loads, one per hd-block hb; lanes cover kv 0..63
      gload16(Kg + (size_t)(kv0 + lane) * 128 + id * 8, (char*)Kl + (id * 64) * 16);
      // V tile: 16 wave-loads: (kvb, hd half); lanes cover 64 hd rows
      int kvb = id >> 1, h0 = (id & 1) * 64;
      gload16(Vg + (size_t)(h0 + lane) * L_SEQ + (kv0 + kvb * 8), (char*)Vl + (kvb * 128 + h0) * 16);
    }
    __syncthreads();

    // S = Q K^T  (16 x 64 per wave)
    f32x4 s[4] = {};
    const f16x8* K8 = (const f16x8*)Kl;
    for (int kk = 0; kk < 4; ++kk) {
      int hb = kk * 4 + quad;
      for (int ni = 0; ni < 4; ++ni) {
        f16x8 bfr = K8[hb * 64 + ni * 16 + l15];
        s[ni] = __builtin_amdgcn_mfma_f32_16x16x32_f16(qf[kk], bfr, s[ni], 0, 0, 0);
      }
    }
    // scale + causal mask (only the diagonal tile needs masking)
    float mx[4];
    bool diag = (t == ntile - 1);
    for (int reg = 0; reg < 4; ++reg) {
      int rowg = q0 + wave * 16 + quad * 4 + reg;
      float m = -1e30f;
      for (int ni = 0; ni < 4; ++ni) {
        float v = s[ni][reg] * scale;
        if (diag && (kv0 + ni * 16 + l15) > rowg) v = -1e30f;
        s[ni][reg] = v;
        m = fmaxf(m, v);
      }
      mx[reg] = m;
    }
    for (int off = 1; off < 16; off <<= 1)
      for (int reg = 0; reg < 4; ++reg)
        mx[reg] = fmaxf(mx[reg], __shfl_xor(mx[reg], off));
    float al[4], rs[4];
    for (int reg = 0; reg < 4; ++reg) {
      float mn = fmaxf(mi[reg], mx[reg]);
      al[reg] = __expf(mi[reg] - mn);  // exp(-1e30 - mn) == 0 on first tile
      mi[reg] = mn;
      rs[reg] = 0.f;
    }
    // P = exp(S - m), write to per-wave LDS in A-operand (k-blocked) layout
    _Float16* Pw = Pl + wave * (16 * 64);
    for (int ni = 0; ni < 4; ++ni) {
      int kv = ni * 16 + l15;
      int pbase = ((kv >> 3) * 16) * 8 + (kv & 7);
      for (int reg = 0; reg < 4; ++reg) {
        float p = __expf(s[ni][reg] - mi[reg]);
        rs[reg] += p;
        Pw[pbase + (quad * 4 + reg) * 8] = (_Float16)p;
      }
    }
    for (int off = 1; off < 16; off <<= 1)
      for (int reg = 0; reg < 4; ++reg)
        rs[reg] += __shfl_xor(rs[reg], off);
    for (int reg = 0; reg < 4; ++reg)
      li[reg] = li[reg] * al[reg] + rs[reg];
    for (int ni = 0; ni < 8; ++ni)
      for (int reg = 0; reg < 4; ++reg)
        o[ni][reg] *= al[reg];
    __asm__ volatile("s_waitcnt lgkmcnt(0)" ::: "memory");  // P writes visible before reread
    // O += P V
    const f16x8* V8 = (const f16x8*)Vl;
    const f16x8* P8 = (const f16x8*)Pw;
    for (int kk = 0; kk < 2; ++kk) {
      f16x8 pf = P8[(kk * 4 + quad) * 16 + l15];
      for (int ni = 0; ni < 8; ++ni) {
        f16x8 vf = V8[(kk * 4 + quad) * 128 + ni * 16 + l15];
        o[ni] = __builtin_amdgcn_mfma_f32_16x16x32_f16(pf, vf, o[ni], 0, 0, 0);
      }
    }
  }
  // epilogue: O / l  -> y[b][l][h*128+hd] fp16
  int b = bh >> 4, h = bh & 15;
  for (int reg = 0; reg < 4; ++reg) {
    float inv = 1.f / li[reg];
    int rowg = q0 + wave * 16 + quad * 4 + reg;
    size_t base = ((size_t)(b * L_SEQ + rowg)) * DMODEL + h * HDIM + l15;
    for (int ni = 0; ni < 8; ++ni)
      y[base + (size_t)ni * 16] = (_Float16)(o[ni][reg] * inv);
  }
}

extern "C" void kernel_launch(void* const* d_in, const int* in_sizes, int n_in,
                              void* d_out, int out_size, void* d_ws, size_t ws_size,
                              hipStream_t stream) {
  const float* x = (const float*)d_in[0];      // [4,2048,2048]
  const float* w_qkv = (const float*)d_in[1];  // [6144,2048]
  const float* w_o = (const float*)d_in[2];    // [2048,2048]
  float* out = (float*)d_out;                  // [4,2048,2048]

  char* ws = (char*)d_ws;
  _Float16* xb = (_Float16*)ws;    ws += (size_t)8192 * 2048 * 2;   // 32 MiB
  _Float16* wqkvb = (_Float16*)ws; ws += (size_t)6144 * 2048 * 2;   // 24 MiB
  _Float16* wob = (_Float16*)ws;   ws += (size_t)2048 * 2048 * 2;   // 8 MiB
  _Float16* qkv = (_Float16*)ws;   ws += (size_t)8192 * 6144 * 2;   // 96 MiB
  _Float16* qt = (_Float16*)ws;    ws += (size_t)64 * 2048 * 128 * 2;
  _Float16* kt = (_Float16*)ws;    ws += (size_t)64 * 2048 * 128 * 2;
  _Float16* vt = (_Float16*)ws;    ws += (size_t)64 * 2048 * 128 * 2;
  _Float16* y = qkv;  // qkv scratch is dead after rope/v_transpose; reuse for attention output

  cvt_f32_f16<<<16384, 256, 0, stream>>>(x, xb, 8192 * 2048);
  cvt_f32_f16<<<12288, 256, 0, stream>>>(w_qkv, wqkvb, 6144 * 2048);
  cvt_f32_f16<<<4096, 256, 0, stream>>>(w_o, wob, 2048 * 2048);

  gemm_bt<_Float16><<<dim3(48 * 64), 256, 0, stream>>>(xb, wqkvb, qkv, 8192, 6144, 2048);
  rope_scatter<<<dim3(8192, 8), 256, 0, stream>>>(qkv, qt, kt);
  v_transpose<<<dim3(32, 2, 64), 256, 0, stream>>>(qkv, vt);
  attn_fwd<<<dim3(32, 64), 256, 0, stream>>>(qt, kt, vt, y);
  gemm_bt<float><<<dim3(16 * 64), 256, 0, stream>>>(y, wob, out, 8192, 2048, 2048);
}

// Round 5
// 837.617 us; speedup vs baseline: 1.3104x; 1.3104x over previous
//
#include <hip/hip_runtime.h>

#define L_SEQ 2048
#define DMODEL 2048
#define NHEAD 16
#define HDIM 128
#define BATCH 4

typedef _Float16 f16x8 __attribute__((ext_vector_type(8)));
typedef _Float16 f16x4 __attribute__((ext_vector_type(4)));
typedef float f32x4 __attribute__((ext_vector_type(4)));

// async global->LDS, 16B per lane. LDS base must be wave-uniform; HW scatters lane*16.
__device__ __forceinline__ void gload16(const void* g, void* l) {
  __builtin_amdgcn_global_load_lds((const __attribute__((address_space(1))) void*)g,
                                   (__attribute__((address_space(3))) void*)l, 16, 0, 0);
}

// fp32 row-major [M][K] -> fp16 blocked tile-image layout:
// tile (mb, kt) of 128 rows x 64 k, stored contiguously (8192 halves = 16KB) in LDS image
// order: 16B-unit index (kb*128 + row), kb = (k&63)>>3, within-unit = k&7.
// Fully coalesced: thread reads 128B contiguous fp32, writes 4x16B at 2KB stride
// (128 threads of same (half,j) cover contiguous 2KB out).
__global__ __launch_bounds__(256) void cvt_blocked(const float* __restrict__ in,
                                                   _Float16* __restrict__ out, int K) {
  const int kt = blockIdx.x, mb = blockIdx.y, KT = K >> 6;
  const int t = threadIdx.x, row = t >> 1, half = t & 1;
  const float* src = in + (size_t)(mb * 128 + row) * K + kt * 64 + half * 32;
  _Float16* tile = out + ((size_t)mb * KT + kt) * 8192;
  for (int j = 0; j < 4; ++j) {
    float4 a = *(const float4*)(src + j * 8);
    float4 b = *(const float4*)(src + j * 8 + 4);
    f16x8 o;
    o[0] = (_Float16)a.x; o[1] = (_Float16)a.y; o[2] = (_Float16)a.z; o[3] = (_Float16)a.w;
    o[4] = (_Float16)b.x; o[5] = (_Float16)b.y; o[6] = (_Float16)b.z; o[7] = (_Float16)b.w;
    int kb = half * 4 + j;
    *(f16x8*)(tile + (size_t)(kb * 128 + row) * 8) = o;
  }
}

// C[M][N] = A * Bt^T, A/Bt in BLOCKED tile-image layout (see cvt_blocked), C row-major.
// 128x128 tile, BK=64, 4 waves 2x2, each wave 64x64 via 4x4 mfma_16x16x32.
// Staging is now perfectly contiguous: each gload16 streams 1KB (16 full lines) vs the
// old 64-partial-line gather (R4 counters: MfmaUtil 21%, VMEM line-request bound).
// XCD-aware swizzle kept (measured neutral). REQUIRES M == 8192 (64 M-tiles).
template <typename OUT>
__global__ __launch_bounds__(256, 4) void gemm_bt(const _Float16* __restrict__ A,
                                                  const _Float16* __restrict__ Bt,
                                                  OUT* __restrict__ C,
                                                  int M, int N, int K) {
  __shared__ _Float16 As[128 * 64];
  __shared__ _Float16 Bs[128 * 64];
  const int KT = K >> 6;
  const int tid = threadIdx.x;
  const int wave = tid >> 6, lane = tid & 63, quad = lane >> 4, l15 = lane & 15;
  const int xcd = blockIdx.x & 7;
  const int lm = blockIdx.x >> 3;
  const int tm = xcd * 8 + (lm & 7);
  const int tn = lm >> 3;
  if (tm * 128 >= M || tn * 128 >= N) return;  // wave-uniform safety guard
  const int wm = (wave >> 1) * 64, wn = (wave & 1) * 64;
  const int id = wave * 4;
  f32x4 acc[4][4] = {};
  for (int kt = 0; kt < KT; ++kt) {
    const _Float16* tA = A + ((size_t)tm * KT + kt) * 8192;
    const _Float16* tB = Bt + ((size_t)tn * KT + kt) * 8192;
    __syncthreads();  // prev-iter LDS reads done before overwrite
    for (int j = 0; j < 4; ++j) {
      gload16(tA + (size_t)(id + j) * 512 + lane * 8, (char*)As + (id + j) * 1024);
      gload16(tB + (size_t)(id + j) * 512 + lane * 8, (char*)Bs + (id + j) * 1024);
    }
    __syncthreads();  // compiler drains vmcnt before barrier
    const f16x8* A8 = (const f16x8*)As;
    const f16x8* B8 = (const f16x8*)Bs;
    for (int kk = 0; kk < 2; ++kk) {
      int kb = kk * 4 + quad;
      f16x8 af[4], bf[4];
      for (int mi = 0; mi < 4; ++mi) af[mi] = A8[kb * 128 + wm + mi * 16 + l15];
      for (int ni = 0; ni < 4; ++ni) bf[ni] = B8[kb * 128 + wn + ni * 16 + l15];
      for (int mi = 0; mi < 4; ++mi)
        for (int ni = 0; ni < 4; ++ni)
          acc[mi][ni] = __builtin_amdgcn_mfma_f32_16x16x32_f16(af[mi], bf[ni], acc[mi][ni], 0, 0, 0);
    }
  }
  // C/D layout: col = lane&15, row = quad*4 + reg  (m89-verified, dtype-independent)
  for (int mi = 0; mi < 4; ++mi)
    for (int ni = 0; ni < 4; ++ni) {
      int r = tm * 128 + wm + mi * 16 + quad * 4;
      int c = tn * 128 + wn + ni * 16 + l15;
      for (int reg = 0; reg < 4; ++reg)
        C[(size_t)(r + reg) * N + c] = (OUT)acc[mi][ni][reg];
    }
}

// qkv[8192][6144] fp16, q/k part only -> rope -> qt,kt:[bh][l][hd]   (coalesced both sides)
__global__ void rope_scatter(const _Float16* __restrict__ qkv,
                             _Float16* __restrict__ qt,
                             _Float16* __restrict__ kt) {
  int row = blockIdx.x;                       // 0..8191 = b*2048 + l
  int pe = blockIdx.y * 256 + threadIdx.x;    // 0..2047 pair index (q,k only)
  int e = pe * 2;
  float x1 = (float)qkv[(size_t)row * 6144 + e];
  float x2 = (float)qkv[(size_t)row * 6144 + e + 1];
  int which = e >> 11;                        // 0=q, 1=k
  int h = (e >> 7) & 15;
  int hd = e & 127;
  int b = row >> 11, l = row & 2047;
  int bh = b * 16 + h;
  int i = hd >> 1;
  // freq = 10000^(-i/64) ; ln(10000)/64 = 0.14391156831212787
  float ang = (float)l * __expf((float)i * -0.14391156831212787f);
  float s, c;
  __sincosf(ang, &s, &c);
  float o1 = x1 * c - x2 * s;
  float o2 = x2 * c + x1 * s;
  _Float16* dst = (which == 0) ? qt : kt;
  size_t base = ((size_t)bh * 2048 + l) * 128 + hd;
  dst[base] = (_Float16)o1;
  dst[base + 1] = (_Float16)o2;
}

// V part of qkv -> vt[bh][hd][l], LDS-tiled 64x64 transpose, coalesced global R/W.
__global__ __launch_bounds__(256) void v_transpose(const _Float16* __restrict__ qkv,
                                                   _Float16* __restrict__ vt) {
  __shared__ _Float16 Ls[64 * 72];
  const int tid = threadIdx.x;
  const int l0 = blockIdx.x * 64;       // 32 tiles
  const int hd0 = blockIdx.y * 64;      // 2 tiles
  const int bh = blockIdx.z;            // 64
  const int b = bh >> 4, h = bh & 15;
  const size_t colbase = 4096 + h * 128 + hd0;
  for (int i = 0; i < 2; ++i) {
    int chunk = tid + i * 256;
    int r = chunk >> 3, c = chunk & 7;
    f16x8 v = *(const f16x8*)(qkv + (size_t)(b * 2048 + l0 + r) * 6144 + colbase + c * 8);
    *(f16x8*)(Ls + r * 72 + c * 8) = v;
  }
  __syncthreads();
  for (int i = 0; i < 2; ++i) {
    int chunk = tid + i * 256;
    int hr = chunk >> 3, c = chunk & 7;
    f16x8 o;
    for (int j = 0; j < 8; ++j) o[j] = Ls[(c * 8 + j) * 72 + hr];
    *(f16x8*)(vt + ((size_t)bh * 128 + hd0 + hr) * 2048 + l0 + c * 8) = o;
  }
}

// Flash attention, causal. Block: 64 q rows (4 waves x 16), KV tiles of 64.
// Epilogue writes y in BLOCKED tile-image layout (input of out-proj GEMM).
__global__ __launch_bounds__(256) void attn_fwd(const _Float16* __restrict__ qt,
                                                const _Float16* __restrict__ kt,
                                                const _Float16* __restrict__ vt,
                                                _Float16* __restrict__ y) {
  __shared__ _Float16 Kl[64 * 128];
  __shared__ _Float16 Vl[64 * 128];
  __shared__ _Float16 Pl[4 * 16 * 64];
  const int q0 = blockIdx.x * 64;
  const int bh = blockIdx.y;
  const int tid = threadIdx.x;
  const int wave = tid >> 6, lane = tid & 63, quad = lane >> 4, l15 = lane & 15;
  const _Float16* Q = qt + (size_t)bh * L_SEQ * HDIM;
  const _Float16* Kg = kt + (size_t)bh * L_SEQ * HDIM;
  const _Float16* Vg = vt + (size_t)bh * HDIM * L_SEQ;

  f16x8 qf[4];
  {
    int qrow = q0 + wave * 16 + l15;
    for (int kk = 0; kk < 4; ++kk)
      qf[kk] = *(const f16x8*)(Q + (size_t)qrow * 128 + kk * 32 + quad * 8);
  }
  f32x4 o[8] = {};
  float mi[4] = {-1e30f, -1e30f, -1e30f, -1e30f};
  float li[4] = {0.f, 0.f, 0.f, 0.f};
  const float scale = 0.08838834764831845f;  // 1/sqrt(128)
  const int ntile = (q0 >> 6) + 1;

  for (int t = 0; t < ntile; ++t) {
    const int kv0 = t * 64;
    __syncthreads();
    for (int j = 0; j < 4; ++j) {
      int id = wave * 4 + j;
      gload16(Kg + (size_t)(kv0 + lane) * 128 + id * 8, (char*)Kl + (id * 64) * 16);
      int kvb = id >> 1, h0 = (id & 1) * 64;
      gload16(Vg + (size_t)(h0 + lane) * L_SEQ + (kv0 + kvb * 8), (char*)Vl + (kvb * 128 + h0) * 16);
    }
    __syncthreads();

    // S = Q K^T  (16 x 64 per wave)
    f32x4 s[4] = {};
    const f16x8* K8 = (const f16x8*)Kl;
    for (int kk = 0; kk < 4; ++kk) {
      int hb = kk * 4 + quad;
      for (int ni = 0; ni < 4; ++ni) {
        f16x8 bfr = K8[hb * 64 + ni * 16 + l15];
        s[ni] = __builtin_amdgcn_mfma_f32_16x16x32_f16(qf[kk], bfr, s[ni], 0, 0, 0);
      }
    }
    float mx[4];
    bool diag = (t == ntile - 1);
    for (int reg = 0; reg < 4; ++reg) {
      int rowg = q0 + wave * 16 + quad * 4 + reg;
      float m = -1e30f;
      for (int ni = 0; ni < 4; ++ni) {
        float v = s[ni][reg] * scale;
        if (diag && (kv0 + ni * 16 + l15) > rowg) v = -1e30f;
        s[ni][reg] = v;
        m = fmaxf(m, v);
      }
      mx[reg] = m;
    }
    for (int off = 1; off < 16; off <<= 1)
      for (int reg = 0; reg < 4; ++reg)
        mx[reg] = fmaxf(mx[reg], __shfl_xor(mx[reg], off));
    float al[4], rs[4];
    for (int reg = 0; reg < 4; ++reg) {
      float mn = fmaxf(mi[reg], mx[reg]);
      al[reg] = __expf(mi[reg] - mn);
      mi[reg] = mn;
      rs[reg] = 0.f;
    }
    _Float16* Pw = Pl + wave * (16 * 64);
    for (int ni = 0; ni < 4; ++ni) {
      int kv = ni * 16 + l15;
      int pbase = ((kv >> 3) * 16) * 8 + (kv & 7);
      for (int reg = 0; reg < 4; ++reg) {
        float p = __expf(s[ni][reg] - mi[reg]);
        rs[reg] += p;
        Pw[pbase + (quad * 4 + reg) * 8] = (_Float16)p;
      }
    }
    for (int off = 1; off < 16; off <<= 1)
      for (int reg = 0; reg < 4; ++reg)
        rs[reg] += __shfl_xor(rs[reg], off);
    for (int reg = 0; reg < 4; ++reg)
      li[reg] = li[reg] * al[reg] + rs[reg];
    for (int ni = 0; ni < 8; ++ni)
      for (int reg = 0; reg < 4; ++reg)
        o[ni][reg] *= al[reg];
    __asm__ volatile("s_waitcnt lgkmcnt(0)" ::: "memory");  // P writes visible before reread
    const f16x8* V8 = (const f16x8*)Vl;
    const f16x8* P8 = (const f16x8*)Pw;
    for (int kk = 0; kk < 2; ++kk) {
      f16x8 pf = P8[(kk * 4 + quad) * 16 + l15];
      for (int ni = 0; ni < 8; ++ni) {
        f16x8 vf = V8[(kk * 4 + quad) * 128 + ni * 16 + l15];
        o[ni] = __builtin_amdgcn_mfma_f32_16x16x32_f16(pf, vf, o[ni], 0, 0, 0);
      }
    }
  }
  // epilogue: O/l -> y in blocked layout: tile (gr>>7, col>>6), unit (((col&63)>>3)*128+(gr&127))*8+(col&7)
  int b = bh >> 4, h = bh & 15;
  for (int reg = 0; reg < 4; ++reg) {
    float inv = 1.f / li[reg];
    int gr = b * L_SEQ + q0 + wave * 16 + quad * 4 + reg;
    int mbt = gr >> 7, row = gr & 127;
    for (int ni = 0; ni < 8; ++ni) {
      int col = h * 128 + ni * 16 + l15;
      int cb = col >> 6, kb = (col >> 3) & 7, wi = col & 7;
      y[((size_t)mbt * 32 + cb) * 8192 + (size_t)(kb * 128 + row) * 8 + wi] =
          (_Float16)(o[ni][reg] * inv);
    }
  }
}

extern "C" void kernel_launch(void* const* d_in, const int* in_sizes, int n_in,
                              void* d_out, int out_size, void* d_ws, size_t ws_size,
                              hipStream_t stream) {
  const float* x = (const float*)d_in[0];      // [4,2048,2048]
  const float* w_qkv = (const float*)d_in[1];  // [6144,2048]
  const float* w_o = (const float*)d_in[2];    // [2048,2048]
  float* out = (float*)d_out;                  // [4,2048,2048]

  char* ws = (char*)d_ws;
  _Float16* xb = (_Float16*)ws;    ws += (size_t)8192 * 2048 * 2;   // 32 MiB blocked
  _Float16* wqkvb = (_Float16*)ws; ws += (size_t)6144 * 2048 * 2;   // 24 MiB blocked
  _Float16* wob = (_Float16*)ws;   ws += (size_t)2048 * 2048 * 2;   // 8 MiB blocked
  _Float16* qkv = (_Float16*)ws;   ws += (size_t)8192 * 6144 * 2;   // 96 MiB row-major
  _Float16* qt = (_Float16*)ws;    ws += (size_t)64 * 2048 * 128 * 2;
  _Float16* kt = (_Float16*)ws;    ws += (size_t)64 * 2048 * 128 * 2;
  _Float16* vt = (_Float16*)ws;    ws += (size_t)64 * 2048 * 128 * 2;
  _Float16* y = qkv;  // qkv dead after rope/v_transpose; y (blocked, 32 MiB) reuses it

  cvt_blocked<<<dim3(32, 64), 256, 0, stream>>>(x, xb, 2048);
  cvt_blocked<<<dim3(32, 48), 256, 0, stream>>>(w_qkv, wqkvb, 2048);
  cvt_blocked<<<dim3(32, 16), 256, 0, stream>>>(w_o, wob, 2048);

  gemm_bt<_Float16><<<dim3(48 * 64), 256, 0, stream>>>(xb, wqkvb, qkv, 8192, 6144, 2048);
  rope_scatter<<<dim3(8192, 8), 256, 0, stream>>>(qkv, qt, kt);
  v_transpose<<<dim3(32, 2, 64), 256, 0, stream>>>(qkv, vt);
  attn_fwd<<<dim3(32, 64), 256, 0, stream>>>(qt, kt, vt, y);
  gemm_bt<float><<<dim3(16 * 64), 256, 0, stream>>>(y, wob, out, 8192, 2048, 2048);
}